// Round 7
// baseline (280.535 us; speedup 1.0000x reference)
//
#include <hip/hip_runtime.h>
#include <stdint.h>

// Problem constants
#define Bsz 4096
#define Tn  64      // scan length (char_seq[:, :-1])
#define T1n 65
#define Hn  64
#define Pn  50
#define Vn  32

typedef __attribute__((ext_vector_type(8))) short short8;
typedef __attribute__((ext_vector_type(4))) short short4v;
typedef __attribute__((ext_vector_type(4))) float floatx4;

__device__ __forceinline__ float bf2f(unsigned short u) {
  union { unsigned int i; float f; } x; x.i = ((unsigned int)u) << 16; return x.f;
}
__device__ __forceinline__ unsigned short f2bf(float f) {
  union { float f; unsigned int i; } x; x.f = f;
  return (unsigned short)((x.i + 0x7FFFu + ((x.i >> 16) & 1u)) >> 16);
}
__device__ __forceinline__ float fast_sigmoid(float x) {
  return __builtin_amdgcn_rcpf(1.f + __expf(-x));
}
__device__ __forceinline__ float fast_tanh(float x) {
  return 1.f - 2.f * __builtin_amdgcn_rcpf(1.f + __expf(2.f * x));
}

// B-frag with pi-permuted K rows: storage index k -> physical row p(k)=(k&3)*16+(k>>2)
__device__ __forceinline__ short8 load_bfrag_pi(const float* __restrict__ W, int ncols, int col, int kbase) {
  short8 f;
#pragma unroll
  for (int j = 0; j < 8; ++j) {
    int k = kbase + j;
    int p = ((k & 3) << 4) | (k >> 2);
    f[j] = (short)f2bf(W[(long)p * ncols + col]);
  }
  return f;
}

// Single-wave-per-block fused GRU: 256 blocks x 64 threads. Each wave owns 16
// batch rows and ALL 64 hidden cols (4 MFMA col-tiles) -> zero inter-wave
// barriers in the serial scan. LDS is wave-private; C->A transform uses the
// pi storage permutation so each transpose is 4 ds_write_b64.
__launch_bounds__(64, 1)
__global__ void gru_all(const float* __restrict__ phon,
                        const int* __restrict__ cs,
                        const float* __restrict__ emb,
                        const float* __restrict__ Wrx, const float* __restrict__ brx,
                        const float* __restrict__ Wrh, const float* __restrict__ brh,
                        const float* __restrict__ Wzx, const float* __restrict__ bzx,
                        const float* __restrict__ Wzh, const float* __restrict__ bzh,
                        const float* __restrict__ Whx, const float* __restrict__ bhx,
                        const float* __restrict__ Whh, const float* __restrict__ bhh,
                        const float* __restrict__ Wpj, const float* __restrict__ bpj_g,
                        float* __restrict__ ws,
                        float* __restrict__ outp) {
  __shared__ __align__(16) unsigned short hist_s[16 * 1152]; // h[slot][m][72], pi storage order
  __shared__ __align__(16) unsigned short rh_s[1152];        // r*h, same layout
  __shared__ __align__(16) unsigned short tblT_s[3 * 2176];  // [g][v][68], pi col order
  __shared__ unsigned int code4_s[T1n * 4];                  // packed codes [t][q]

  const int lane = threadIdx.x;
  const int q = lane >> 4, c16 = lane & 15;
  const int b0 = blockIdx.x * 16;
  const floatx4 zf = {0.f, 0.f, 0.f, 0.f};

  // int32-vs-int64 detection (int64 codes 0..31 have all-zero odd words)
  const bool is64 = (__ballot(cs[2 * lane + 1] != 0) == 0ull);

  // packed codes: code4_s[t*4+qq] = codes of rows qq*4..qq*4+3 at step t
#pragma unroll
  for (int kk = 0; kk < 5; ++kk) {
    int idx = lane + 64 * kk;
    if (idx < T1n * 4) {
      int t = idx >> 2, qq = idx & 3;
      unsigned int pk = 0;
#pragma unroll
      for (int r = 0; r < 4; ++r) {
        long id = (long)(b0 + qq * 4 + r) * T1n + t;
        int c = is64 ? cs[2 * id] : cs[id];
        pk |= ((unsigned int)(c & 255)) << (8 * r);
      }
      code4_s[idx] = pk;
    }
  }
  for (int i = lane; i < 1152; i += 64) hist_s[15 * 1152 + i] = 0;  // h0 slot

  // ---- recurrent + proj B-frags in registers (pi K-order, t-invariant) ----
  short8 Brh[4][2], Bzh[4][2], Bhh[4][2], Bpj[2][2];
#pragma unroll
  for (int T = 0; T < 4; ++T)
#pragma unroll
    for (int hh = 0; hh < 2; ++hh) {
      Brh[T][hh] = load_bfrag_pi(Wrh, Hn, T * 16 + c16, hh * 32 + q * 8);
      Bzh[T][hh] = load_bfrag_pi(Wzh, Hn, T * 16 + c16, hh * 32 + q * 8);
      Bhh[T][hh] = load_bfrag_pi(Whh, Hn, T * 16 + c16, hh * 32 + q * 8);
    }
#pragma unroll
  for (int vt = 0; vt < 2; ++vt)
#pragma unroll
    for (int hh = 0; hh < 2; ++hh)
      Bpj[vt][hh] = load_bfrag_pi(Wpj, Vn, vt * 16 + c16, hh * 32 + q * 8);
  const float bpj0 = bpj_g[c16], bpj1 = bpj_g[16 + c16];

  // ---- TBL via MFMA: tbl[v][j] = emb[v] @ W_gx[:64] + b_gx[j] + b_gh[j] ----
  for (int g = 0; g < 3; ++g) {
    const float* W  = (g == 0) ? Wrx : (g == 1) ? Wzx : Whx;
    const float* bx = (g == 0) ? brx : (g == 1) ? bzx : bhx;
    const float* bh = (g == 0) ? brh : (g == 1) ? bzh : bhh;
    short8 Bx[4][2];
#pragma unroll
    for (int T = 0; T < 4; ++T)
#pragma unroll
      for (int hh = 0; hh < 2; ++hh) {
        short8 f;
#pragma unroll
        for (int j = 0; j < 8; ++j)
          f[j] = (short)f2bf(W[(long)(hh * 32 + q * 8 + j) * Hn + T * 16 + c16]);
        Bx[T][hh] = f;
      }
    float bias[4];
#pragma unroll
    for (int T = 0; T < 4; ++T) bias[T] = bx[T * 16 + c16] + bh[T * 16 + c16];
    for (int mt = 0; mt < 2; ++mt) {
      short8 A0, A1;
#pragma unroll
      for (int j = 0; j < 8; ++j) {
        A0[j] = (short)f2bf(emb[(long)(mt * 16 + c16) * Hn + q * 8 + j]);
        A1[j] = (short)f2bf(emb[(long)(mt * 16 + c16) * Hn + 32 + q * 8 + j]);
      }
      floatx4 acc[4];
#pragma unroll
      for (int T = 0; T < 4; ++T) {
        acc[T] = __builtin_amdgcn_mfma_f32_16x16x32_bf16(A0, Bx[T][0], zf, 0, 0, 0);
        acc[T] = __builtin_amdgcn_mfma_f32_16x16x32_bf16(A1, Bx[T][1], acc[T], 0, 0, 0);
      }
#pragma unroll
      for (int r = 0; r < 4; ++r) {
        short4v tv;
#pragma unroll
        for (int T = 0; T < 4; ++T) tv[T] = (short)f2bf(acc[T][r] + bias[T]);
        int v = mt * 16 + q * 4 + r;
        *(short4v*)&tblT_s[g * 2176 + v * 68 + c16 * 4] = tv;
      }
    }
  }

  // ---- PH via MFMA: ph[m][j] = phon[b0+m] @ W_gx[64:114]; K=50 padded to 64 ----
  floatx4 ph_r[4], ph_z[4], ph_h[4];
  {
    short8 Ap0, Ap1;
#pragma unroll
    for (int j = 0; j < 8; ++j) {
      int k0 = q * 8 + j;                 // < 32 < 50 always
      Ap0[j] = (short)f2bf(phon[(long)(b0 + c16) * Pn + k0]);
      int k1 = 32 + q * 8 + j;
      Ap1[j] = (k1 < Pn) ? (short)f2bf(phon[(long)(b0 + c16) * Pn + k1]) : (short)0;
    }
    for (int g = 0; g < 3; ++g) {
      const float* W = (g == 0) ? Wrx : (g == 1) ? Wzx : Whx;
      short8 Bp[4][2];
#pragma unroll
      for (int T = 0; T < 4; ++T)
#pragma unroll
        for (int hh = 0; hh < 2; ++hh) {
          short8 f;
#pragma unroll
          for (int j = 0; j < 8; ++j) {
            int k = hh * 32 + q * 8 + j;
            f[j] = (k < Pn) ? (short)f2bf(W[(long)(Hn + k) * Hn + T * 16 + c16]) : (short)0;
          }
          Bp[T][hh] = f;
        }
#pragma unroll
      for (int T = 0; T < 4; ++T) {
        floatx4 acc = __builtin_amdgcn_mfma_f32_16x16x32_bf16(Ap0, Bp[T][0], zf, 0, 0, 0);
        acc = __builtin_amdgcn_mfma_f32_16x16x32_bf16(Ap1, Bp[T][1], acc, 0, 0, 0);
        if (g == 0) ph_r[T] = acc; else if (g == 1) ph_z[T] = acc; else ph_h[T] = acc;
      }
    }
  }

  floatx4 h4[4] = {zf, zf, zf, zf};
  float nll = 0.f, cnt = 0.f;
  __syncthreads();  // single wave: just a waitcnt

  for (int qi = 0; qi < 4; ++qi) {
    // ---- 16-step scan chunk: wave-private LDS, no global traffic ----
    for (int tt = 0; tt < 16; ++tt) {
      const int t = qi * 16 + tt;
      const unsigned short* hp = &hist_s[((tt + 15) & 15) * 1152];
      short8 a0 = *(const short8*)&hp[c16 * 72 + q * 8];
      short8 a1 = *(const short8*)&hp[c16 * 72 + 32 + q * 8];
      floatx4 accr[4], accz[4];
#pragma unroll
      for (int T = 0; T < 4; ++T) {
        accr[T] = __builtin_amdgcn_mfma_f32_16x16x32_bf16(a0, Brh[T][0], zf, 0, 0, 0);
        accr[T] = __builtin_amdgcn_mfma_f32_16x16x32_bf16(a1, Brh[T][1], accr[T], 0, 0, 0);
        accz[T] = __builtin_amdgcn_mfma_f32_16x16x32_bf16(a0, Bzh[T][0], zf, 0, 0, 0);
        accz[T] = __builtin_amdgcn_mfma_f32_16x16x32_bf16(a1, Bzh[T][1], accz[T], 0, 0, 0);
      }
      unsigned int pk = code4_s[t * 4 + q];
      floatx4 zz[4];
#pragma unroll
      for (int r = 0; r < 4; ++r) {
        int cr = (pk >> (8 * r)) & 255;
        short4v t0 = *(const short4v*)&tblT_s[0 * 2176 + cr * 68 + c16 * 4];
        short4v t1 = *(const short4v*)&tblT_s[1 * 2176 + cr * 68 + c16 * 4];
        short4v rhp;
#pragma unroll
        for (int T = 0; T < 4; ++T) {
          float xr = bf2f((unsigned short)t0[T]) + ph_r[T][r] + accr[T][r];
          float rr = fast_sigmoid(xr);
          float xz = bf2f((unsigned short)t1[T]) + ph_z[T][r] + accz[T][r];
          zz[T][r] = fast_sigmoid(xz);
          rhp[T] = (short)f2bf(rr * h4[T][r]);
        }
        *(short4v*)&rh_s[(q * 4 + r) * 72 + c16 * 4] = rhp;  // pi storage order
      }
      __syncthreads();  // lgkm drain only (1 wave)

      short8 p0 = *(const short8*)&rh_s[c16 * 72 + q * 8];
      short8 p1 = *(const short8*)&rh_s[c16 * 72 + 32 + q * 8];
      floatx4 accc[4];
#pragma unroll
      for (int T = 0; T < 4; ++T) {
        accc[T] = __builtin_amdgcn_mfma_f32_16x16x32_bf16(p0, Bhh[T][0], zf, 0, 0, 0);
        accc[T] = __builtin_amdgcn_mfma_f32_16x16x32_bf16(p1, Bhh[T][1], accc[T], 0, 0, 0);
      }
      unsigned short* hw = &hist_s[tt * 1152];
#pragma unroll
      for (int r = 0; r < 4; ++r) {
        int cr = (pk >> (8 * r)) & 255;
        short4v t2 = *(const short4v*)&tblT_s[2 * 2176 + cr * 68 + c16 * 4];
        short4v hb;
#pragma unroll
        for (int T = 0; T < 4; ++T) {
          float xh = bf2f((unsigned short)t2[T]) + ph_h[T][r] + accc[T][r];
          float c = fast_tanh(xh);
          float hn = (1.f - zz[T][r]) * h4[T][r] + zz[T][r] * c;
          h4[T][r] = hn;
          hb[T] = (short)f2bf(hn);
        }
        *(short4v*)&hw[(q * 4 + r) * 72 + c16 * 4] = hb;
      }
      __syncthreads();  // lgkm drain only
    }

    // ---- per-chunk tail: projection + log-softmax + NLL (stores leave in flight) ----
    for (int tt = 0; tt < 16; ++tt) {
      const int t = qi * 16 + tt;
      const unsigned short* hp = &hist_s[tt * 1152];
      short8 ha0 = *(const short8*)&hp[c16 * 72 + q * 8];
      short8 ha1 = *(const short8*)&hp[c16 * 72 + 32 + q * 8];
      floatx4 l0 = __builtin_amdgcn_mfma_f32_16x16x32_bf16(ha0, Bpj[0][0], zf, 0, 0, 0);
      l0 = __builtin_amdgcn_mfma_f32_16x16x32_bf16(ha1, Bpj[0][1], l0, 0, 0, 0);
      floatx4 l1 = __builtin_amdgcn_mfma_f32_16x16x32_bf16(ha0, Bpj[1][0], zf, 0, 0, 0);
      l1 = __builtin_amdgcn_mfma_f32_16x16x32_bf16(ha1, Bpj[1][1], l1, 0, 0, 0);
      unsigned int pk1 = code4_s[(t + 1) * 4 + q];
#pragma unroll
      for (int r = 0; r < 4; ++r) {
        float lg0 = l0[r] + bpj0, lg1 = l1[r] + bpj1;
        // |logits| <= ~8: exp-sum without max subtraction is safe in fp32
        float s = __expf(lg0) + __expf(lg1);
#pragma unroll
        for (int off = 8; off >= 1; off >>= 1) s += __shfl_xor(s, off);  // quad-local
        float lse = __logf(s);
        int m = q * 4 + r;
        long base = (((long)(b0 + m)) * Tn + t) * Vn;
        outp[base + c16] = lg0;
        outp[base + 16 + c16] = lg1;
        int targ = (pk1 >> (8 * r)) & 255;
        if (targ != 0 && c16 == (targ & 15)) {
          float lt = (targ >> 4) ? lg1 : lg0;
          nll += lse - lt; cnt += 1.f;
        }
      }
    }
    __syncthreads();  // order hist_s reuse for next chunk (lgkm only)
  }

  // wave reduction -> per-block ws slot (plain writes; loss kernel reduces)
#pragma unroll
  for (int off = 32; off >= 1; off >>= 1) {
    nll += __shfl_xor(nll, off);
    cnt += __shfl_xor(cnt, off);
  }
  if (lane == 0) { ws[2 * blockIdx.x] = nll; ws[2 * blockIdx.x + 1] = cnt; }
}

__global__ void loss_kernel(const float* __restrict__ ws, float* __restrict__ outp) {
  int lane = threadIdx.x;  // 64 threads
  float n = 0.f, c = 0.f;
  for (int i = lane; i < 256; i += 64) { n += ws[2 * i]; c += ws[2 * i + 1]; }
#pragma unroll
  for (int off = 32; off >= 1; off >>= 1) {
    n += __shfl_xor(n, off);
    c += __shfl_xor(c, off);
  }
  if (lane == 0) outp[(size_t)Bsz * Tn * Vn] = n / fmaxf(c, 1.f);
}

extern "C" void kernel_launch(void* const* d_in, const int* in_sizes, int n_in,
                              void* d_out, int out_size, void* d_ws, size_t ws_size,
                              hipStream_t stream) {
  const float* phon = (const float*)d_in[0];
  const int*   cs   = (const int*)d_in[1];
  const float* emb  = (const float*)d_in[2];
  const float* Wrx  = (const float*)d_in[3];
  const float* brx  = (const float*)d_in[4];
  const float* Wrh  = (const float*)d_in[5];
  const float* brh  = (const float*)d_in[6];
  const float* Wzx  = (const float*)d_in[7];
  const float* bzx  = (const float*)d_in[8];
  const float* Wzh  = (const float*)d_in[9];
  const float* bzh  = (const float*)d_in[10];
  const float* Whx  = (const float*)d_in[11];
  const float* bhx  = (const float*)d_in[12];
  const float* Whh  = (const float*)d_in[13];
  const float* bhh  = (const float*)d_in[14];
  const float* Wpj  = (const float*)d_in[15];
  const float* bpj  = (const float*)d_in[16];
  float* ws = (float*)d_ws;

  hipLaunchKernelGGL(gru_all, dim3(Bsz / 16), dim3(64), 0, stream,
                     phon, cs, emb, Wrx, brx, Wrh, brh, Wzx, bzx, Wzh, bzh,
                     Whx, bhx, Whh, bhh, Wpj, bpj, ws, (float*)d_out);
  hipLaunchKernelGGL(loss_kernel, dim3(1), dim3(64), 0, stream, ws, (float*)d_out);
}

// Round 8
// 207.165 us; speedup vs baseline: 1.3542x; 1.3542x over previous
//
#include <hip/hip_runtime.h>
#include <stdint.h>

// Problem constants
#define Bsz 4096
#define Tn  64      // scan length (char_seq[:, :-1])
#define T1n 65
#define Hn  64
#define Pn  50
#define Vn  32
#define RPB 8       // real batch rows per block (MFMA M=16 half-occupied ->
                    // 512 blocks = 2 waves/SIMD for stall overlap)

typedef __attribute__((ext_vector_type(8))) short short8;
typedef __attribute__((ext_vector_type(4))) float floatx4;

__device__ __forceinline__ float bf2f(unsigned short u) {
  union { unsigned int i; float f; } x; x.i = ((unsigned int)u) << 16; return x.f;
}
__device__ __forceinline__ unsigned short f2bf(float f) {
  union { float f; unsigned int i; } x; x.f = f;
  return (unsigned short)((x.i + 0x7FFFu + ((x.i >> 16) & 1u)) >> 16);
}
__device__ __forceinline__ float fast_sigmoid(float x) {
  return __builtin_amdgcn_rcpf(1.f + __expf(-x));   // v_rcp, not IEEE div
}
__device__ __forceinline__ float fast_tanh(float x) {
  return 1.f - 2.f * __builtin_amdgcn_rcpf(1.f + __expf(2.f * x));
}

// B-operand fragment for mfma_f32_16x16x32_bf16 from row-major (K x ncols) fp32 weights.
// lane holds n = col, k = kbase + j, j=0..7
__device__ __forceinline__ short8 load_bfrag(const float* __restrict__ W, int ncols, int col, int kbase) {
  short8 f;
#pragma unroll
  for (int j = 0; j < 8; ++j) f[j] = (short)f2bf(W[(long)(kbase + j) * ncols + col]);
  return f;
}

// Fused GRU. 512 blocks x 256 threads (4 waves). Block owns RPB=8 batch rows
// (MFMA rows 8-15 carry clamped duplicates, never stored); wave w owns hidden
// cols [16w,16w+16) in MFMA C-layout (row=quad*4+reg, col=lane&15). h history
// in LDS per 16-step chunk; projection/softmax tails per chunk.
__launch_bounds__(256)
__global__ void gru_kernel(const float* __restrict__ phon,
                           const int* __restrict__ cs,
                           const float* __restrict__ emb,
                           const float* __restrict__ Wrx, const float* __restrict__ brx,
                           const float* __restrict__ Wrh, const float* __restrict__ brh,
                           const float* __restrict__ Wzx, const float* __restrict__ bzx,
                           const float* __restrict__ Wzh, const float* __restrict__ bzh,
                           const float* __restrict__ Whx, const float* __restrict__ bhx,
                           const float* __restrict__ Whh, const float* __restrict__ bhh,
                           const float* __restrict__ Wpj, const float* __restrict__ bpj_g,
                           float* __restrict__ ws,
                           float* __restrict__ outp) {
  __shared__ unsigned short tbl_s[3 * 32 * 66];              // bf16 [g][v][66] (+2 pad)
  __shared__ __align__(16) unsigned short hist_s[16 * 1152]; // bf16 h[t&15][m][72]
  __shared__ __align__(16) unsigned short rh_s[16 * 72];     // bf16 r*h, stride 72
  __shared__ unsigned char code_s[16 * 68];                  // [m][t], t=0..64
  __shared__ unsigned short emb_s[32 * 64];                  // bf16 emb table
  __shared__ unsigned short ph_s[16 * 52];                   // bf16 phon rows, stride 52
  __shared__ int det_s[1];
  __shared__ float red_s[8];

  const int tid = threadIdx.x;
  const int b0 = blockIdx.x * RPB;
  const int w = tid >> 6, lane = tid & 63, q = lane >> 4, c16 = lane & 15;
  const int jcol = w * 16 + c16;

  // --- int32-vs-int64 detection for char_seq (int64 codes 0..31 have zero odd words) ---
  if (tid == 0) det_s[0] = 0;
  __syncthreads();
  if (tid < 128 && cs[2 * tid + 1] != 0) atomicOr(&det_s[0], 1);
  __syncthreads();
  const bool is64 = (det_s[0] == 0);

  // --- staging (rows >= RPB clamp to row RPB-1: finite duplicates, never stored) ---
  for (int i = tid; i < 16 * 72; i += 256) hist_s[15 * 1152 + i] = 0;  // h0 = 0 slot
  for (int i = tid; i < 32 * 64; i += 256) emb_s[i] = f2bf(emb[i]);
  for (int i = tid; i < 16 * Pn; i += 256) {
    int m = i / Pn, p = i - m * Pn;
    int mc = (m < RPB) ? m : RPB - 1;
    ph_s[m * 52 + p] = f2bf(phon[(long)(b0 + mc) * Pn + p]);
  }
  for (int i = tid; i < 16 * T1n; i += 256) {
    int m = i / T1n, t = i - m * T1n;
    int mc = (m < RPB) ? m : RPB - 1;
    long idx = (long)(b0 + mc) * T1n + t;
    int c = is64 ? cs[2 * idx] : cs[idx];
    code_s[m * 68 + t] = (unsigned char)c;
  }

  // weight B-fragments in registers (t-invariant)
  short8 Brh0 = load_bfrag(Wrh, Hn, jcol, q * 8);
  short8 Brh1 = load_bfrag(Wrh, Hn, jcol, 32 + q * 8);
  short8 Bzh0 = load_bfrag(Wzh, Hn, jcol, q * 8);
  short8 Bzh1 = load_bfrag(Wzh, Hn, jcol, 32 + q * 8);
  short8 Bhh0 = load_bfrag(Whh, Hn, jcol, q * 8);
  short8 Bhh1 = load_bfrag(Whh, Hn, jcol, 32 + q * 8);
  // projection fragments: every wave projects its own t's (full 64x32 W_proj)
  short8 Bp00 = load_bfrag(Wpj, Vn, c16,      q * 8);       // vocab tile 0, k 0..31
  short8 Bp01 = load_bfrag(Wpj, Vn, c16,      32 + q * 8);  // vocab tile 0, k 32..63
  short8 Bp10 = load_bfrag(Wpj, Vn, 16 + c16, q * 8);       // vocab tile 1
  short8 Bp11 = load_bfrag(Wpj, Vn, 16 + c16, 32 + q * 8);
  const float bpj0 = bpj_g[c16], bpj1 = bpj_g[16 + c16];

  __syncthreads();

  // --- TBL: tbl_s[g][v][j] = bf16( emb[v] @ W_gx[:64] + b_gx[j] + b_gh[j] ) ---
  for (int g = 0; g < 3; ++g) {
    const float* W  = (g == 0) ? Wrx : (g == 1) ? Wzx : Whx;
    const float* bx = (g == 0) ? brx : (g == 1) ? bzx : bhx;
    const float* bh = (g == 0) ? brh : (g == 1) ? bzh : bhh;
    float acc[8] = {0.f, 0.f, 0.f, 0.f, 0.f, 0.f, 0.f, 0.f};
    float bias = bx[lane] + bh[lane];
    for (int d = 0; d < Hn; ++d) {
      float wv = W[(long)d * Hn + lane];
#pragma unroll
      for (int k = 0; k < 8; ++k)
        acc[k] += bf2f(emb_s[(w + 4 * k) * Hn + d]) * wv;
    }
#pragma unroll
    for (int k = 0; k < 8; ++k)
      tbl_s[g * 2112 + (w + 4 * k) * 66 + lane] = f2bf(acc[k] + bias);
  }

  // --- PH: per-lane registers, rows q*4+r (clamped data for fake rows), col jcol ---
  float ph_r[4] = {0.f, 0.f, 0.f, 0.f};
  float ph_z[4] = {0.f, 0.f, 0.f, 0.f};
  float ph_h[4] = {0.f, 0.f, 0.f, 0.f};
  for (int p = 0; p < Pn; ++p) {
    float wr = Wrx[(long)(Hn + p) * Hn + jcol];
    float wz = Wzx[(long)(Hn + p) * Hn + jcol];
    float wh = Whx[(long)(Hn + p) * Hn + jcol];
#pragma unroll
    for (int r = 0; r < 4; ++r) {
      float xv = bf2f(ph_s[(q * 4 + r) * 52 + p]);
      ph_r[r] += xv * wr; ph_z[r] += xv * wz; ph_h[r] += xv * wh;
    }
  }

  float h[4] = {0.f, 0.f, 0.f, 0.f};
  float nll_acc = 0.f, cnt_acc = 0.f;

  __syncthreads();   // tbl_s ready; hist_s[15] zeroed

  for (int qi = 0; qi < 4; ++qi) {
    // ---- 16-step scan chunk: LDS only, 2 barriers/step ----
    for (int tt = 0; tt < 16; ++tt) {
      const int t = qi * 16 + tt;
      int cr[4];
#pragma unroll
      for (int r = 0; r < 4; ++r) cr[r] = code_s[(q * 4 + r) * 68 + t];

      // phase 1: r,z = sigmoid(TBL[code] + PH + h @ W); h_{t-1} in hist_s[(tt+15)&15]
      const unsigned short* hp = &hist_s[((tt + 15) & 15) * 1152];
      short8 a0 = *(const short8*)&hp[c16 * 72 + q * 8];
      short8 a1 = *(const short8*)&hp[c16 * 72 + 32 + q * 8];
      floatx4 accr = {0.f, 0.f, 0.f, 0.f}, accz = {0.f, 0.f, 0.f, 0.f};
      accr = __builtin_amdgcn_mfma_f32_16x16x32_bf16(a0, Brh0, accr, 0, 0, 0);
      accr = __builtin_amdgcn_mfma_f32_16x16x32_bf16(a1, Brh1, accr, 0, 0, 0);
      accz = __builtin_amdgcn_mfma_f32_16x16x32_bf16(a0, Bzh0, accz, 0, 0, 0);
      accz = __builtin_amdgcn_mfma_f32_16x16x32_bf16(a1, Bzh1, accz, 0, 0, 0);
      float z[4];
#pragma unroll
      for (int r = 0; r < 4; ++r) {
        float xr = bf2f(tbl_s[0 * 2112 + cr[r] * 66 + jcol]) + ph_r[r] + accr[r];
        float rr = fast_sigmoid(xr);
        float xz = bf2f(tbl_s[1 * 2112 + cr[r] * 66 + jcol]) + ph_z[r] + accz[r];
        z[r] = fast_sigmoid(xz);
        rh_s[(q * 4 + r) * 72 + jcol] = f2bf(rr * h[r]);
      }
      __syncthreads();  // A (lgkm only)

      // phase 2: c = tanh(TBL + PH + (r*h) @ W_hh); h = (1-z)h + z c -> hist_s[tt]
      short8 p0 = *(const short8*)&rh_s[c16 * 72 + q * 8];
      short8 p1 = *(const short8*)&rh_s[c16 * 72 + 32 + q * 8];
      floatx4 accc = {0.f, 0.f, 0.f, 0.f};
      accc = __builtin_amdgcn_mfma_f32_16x16x32_bf16(p0, Bhh0, accc, 0, 0, 0);
      accc = __builtin_amdgcn_mfma_f32_16x16x32_bf16(p1, Bhh1, accc, 0, 0, 0);
      unsigned short* hw = &hist_s[tt * 1152];
#pragma unroll
      for (int r = 0; r < 4; ++r) {
        float xh = bf2f(tbl_s[2 * 2112 + cr[r] * 66 + jcol]) + ph_h[r] + accc[r];
        float c = fast_tanh(xh);
        float hn = (1.f - z[r]) * h[r] + z[r] * c;
        h[r] = hn;
        hw[(q * 4 + r) * 72 + jcol] = f2bf(hn);
      }
      __syncthreads();  // B (lgkm only)
    }

    // ---- mini-tail: projection + log-softmax + NLL for this chunk ----
    // wave w owns tt = 4*k + w; reads hist_s, writes logits (real rows only).
    for (int k = 0; k < 4; ++k) {
      const int tt = k * 4 + w;
      const int t = qi * 16 + tt;
      const unsigned short* hp = &hist_s[tt * 1152];
      const short8 ha0 = *(const short8*)&hp[c16 * 72 + q * 8];
      const short8 ha1 = *(const short8*)&hp[c16 * 72 + 32 + q * 8];
      floatx4 l0 = {0.f, 0.f, 0.f, 0.f}, l1 = {0.f, 0.f, 0.f, 0.f};
      l0 = __builtin_amdgcn_mfma_f32_16x16x32_bf16(ha0, Bp00, l0, 0, 0, 0);
      l0 = __builtin_amdgcn_mfma_f32_16x16x32_bf16(ha1, Bp01, l0, 0, 0, 0);
      l1 = __builtin_amdgcn_mfma_f32_16x16x32_bf16(ha0, Bp10, l1, 0, 0, 0);
      l1 = __builtin_amdgcn_mfma_f32_16x16x32_bf16(ha1, Bp11, l1, 0, 0, 0);
#pragma unroll
      for (int r = 0; r < 4; ++r) {
        int m = q * 4 + r;                       // batch sub-row (C layout)
        float lg0 = l0[r] + bpj0, lg1 = l1[r] + bpj1;
        float mx = fmaxf(lg0, lg1);
#pragma unroll
        for (int off = 8; off >= 1; off >>= 1) mx = fmaxf(mx, __shfl_xor(mx, off));
        float s = __expf(lg0 - mx) + __expf(lg1 - mx);
#pragma unroll
        for (int off = 8; off >= 1; off >>= 1) s += __shfl_xor(s, off);
        if (m < RPB) {
          float lse = mx + __logf(s);
          long base = (((long)(b0 + m)) * Tn + t) * Vn;
          outp[base + c16] = lg0;
          outp[base + 16 + c16] = lg1;
          int targ = code_s[m * 68 + t + 1];
          if (targ != 0 && c16 == (targ & 15)) {
            float lt = (targ >> 4) ? lg1 : lg0;
            nll_acc += lse - lt; cnt_acc += 1.f;
          }
        }
      }
    }
    __syncthreads();  // WAR: hist_s reused by next chunk
  }

  // block reduction -> per-block slot in ws (plain writes, no pre-zero)
#pragma unroll
  for (int off = 32; off >= 1; off >>= 1) {
    nll_acc += __shfl_xor(nll_acc, off);
    cnt_acc += __shfl_xor(cnt_acc, off);
  }
  if (lane == 0) { red_s[w] = nll_acc; red_s[4 + w] = cnt_acc; }
  __syncthreads();
  if (tid == 0) {
    ws[2 * blockIdx.x]     = red_s[0] + red_s[1] + red_s[2] + red_s[3];
    ws[2 * blockIdx.x + 1] = red_s[4] + red_s[5] + red_s[6] + red_s[7];
  }
}

__global__ void loss_kernel(const float* __restrict__ ws, float* __restrict__ outp) {
  int lane = threadIdx.x;  // 64 threads
  float n = 0.f, c = 0.f;
  for (int i = lane; i < Bsz / RPB; i += 64) { n += ws[2 * i]; c += ws[2 * i + 1]; }
#pragma unroll
  for (int off = 32; off >= 1; off >>= 1) {
    n += __shfl_xor(n, off);
    c += __shfl_xor(c, off);
  }
  if (lane == 0) outp[(size_t)Bsz * Tn * Vn] = n / fmaxf(c, 1.f);
}

extern "C" void kernel_launch(void* const* d_in, const int* in_sizes, int n_in,
                              void* d_out, int out_size, void* d_ws, size_t ws_size,
                              hipStream_t stream) {
  const float* phon = (const float*)d_in[0];
  const int*   cs   = (const int*)d_in[1];
  const float* emb  = (const float*)d_in[2];
  const float* Wrx  = (const float*)d_in[3];
  const float* brx  = (const float*)d_in[4];
  const float* Wrh  = (const float*)d_in[5];
  const float* brh  = (const float*)d_in[6];
  const float* Wzx  = (const float*)d_in[7];
  const float* bzx  = (const float*)d_in[8];
  const float* Wzh  = (const float*)d_in[9];
  const float* bzh  = (const float*)d_in[10];
  const float* Whx  = (const float*)d_in[11];
  const float* bhx  = (const float*)d_in[12];
  const float* Whh  = (const float*)d_in[13];
  const float* bhh  = (const float*)d_in[14];
  const float* Wpj  = (const float*)d_in[15];
  const float* bpj  = (const float*)d_in[16];
  float* ws = (float*)d_ws;

  hipLaunchKernelGGL(gru_kernel, dim3(Bsz / RPB), dim3(256), 0, stream,
                     phon, cs, emb, Wrx, brx, Wrh, brh, Wzx, bzx, Wzh, bzh,
                     Whx, bhx, Whh, bhh, Wpj, bpj, ws, (float*)d_out);
  hipLaunchKernelGGL(loss_kernel, dim3(1), dim3(64), 0, stream, ws, (float*)d_out);
}

// Round 9
// 175.077 us; speedup vs baseline: 1.6024x; 1.1833x over previous
//
#include <hip/hip_runtime.h>
#include <stdint.h>

// Problem constants
#define Bsz 4096
#define Tn  64      // scan length (char_seq[:, :-1])
#define T1n 65
#define Hn  64
#define Pn  50
#define Vn  32

typedef __attribute__((ext_vector_type(8))) short short8;
typedef __attribute__((ext_vector_type(4))) float floatx4;

__device__ __forceinline__ float bf2f(unsigned short u) {
  union { unsigned int i; float f; } x; x.i = ((unsigned int)u) << 16; return x.f;
}
__device__ __forceinline__ unsigned short f2bf(float f) {
  union { float f; unsigned int i; } x; x.f = f;
  return (unsigned short)((x.i + 0x7FFFu + ((x.i >> 16) & 1u)) >> 16);
}
__device__ __forceinline__ float fast_sigmoid(float x) {
  return __builtin_amdgcn_rcpf(1.f + __expf(-x));
}
__device__ __forceinline__ float fast_tanh(float x) {
  return 1.f - 2.f * __builtin_amdgcn_rcpf(1.f + __expf(2.f * x));
}

// B-operand fragment for mfma_f32_16x16x32_bf16 from row-major (K x ncols) fp32 weights.
__device__ __forceinline__ short8 load_bfrag(const float* __restrict__ W, int ncols, int col, int kbase) {
  short8 f;
#pragma unroll
  for (int j = 0; j < 8; ++j) f[j] = (short)f2bf(W[(long)(kbase + j) * ncols + col]);
  return f;
}

// Producer/consumer fused GRU: 256 blocks x 512 threads (8 waves).
// Block owns 16 batch rows. Waves 0-3 (scan): r-gate (interval A) + c-gate/
// h-update (interval B) for cols [16w,16w+16). Waves 4-7 (aux): z-gate in A
// (f32 -> z_s, consumed by scan waves in B); waves 4-5 also project h_{t-1}
// in B (fp32 logits staged in LDS). Every 8 steps all 8 waves run the
// softmax/NLL/dump tail (single vmcnt drain per chunk). 2 waves/SIMD with
// fully distinct work.
__launch_bounds__(512)
__global__ void gru_kernel(const float* __restrict__ phon,
                           const int* __restrict__ cs,
                           const float* __restrict__ emb,
                           const float* __restrict__ Wrx, const float* __restrict__ brx,
                           const float* __restrict__ Wrh, const float* __restrict__ brh,
                           const float* __restrict__ Wzx, const float* __restrict__ bzx,
                           const float* __restrict__ Wzh, const float* __restrict__ bzh,
                           const float* __restrict__ Whx, const float* __restrict__ bhx,
                           const float* __restrict__ Whh, const float* __restrict__ bhh,
                           const float* __restrict__ Wpj, const float* __restrict__ bpj_g,
                           float* __restrict__ ws,
                           float* __restrict__ outp) {
  __shared__ unsigned short tbl_s[3 * 32 * 66];             // bf16 [g][v][66]
  __shared__ __align__(16) unsigned short hist_s[8 * 1152]; // bf16 h[t&7][m][72]
  __shared__ __align__(16) unsigned short rh_s[1152];       // bf16 r*h [m][72]
  __shared__ float z_s[16 * 68];                            // f32 z [m][68]
  __shared__ float logit_s[8 * 16 * 33];                    // f32 [page&7][m][33]
  __shared__ unsigned int code4_s[(T1n + 1) * 4];           // packed codes [t][q]
  __shared__ int det_s[1];
  __shared__ float red_s[16];

  const int tid = threadIdx.x;
  const int b0 = blockIdx.x * 16;
  const int W8 = tid >> 6, lane = tid & 63, q = lane >> 4, c16 = lane & 15;
  const bool isScan = (W8 < 4);
  const int w = isScan ? W8 : (W8 - 4);
  const int jcol = w * 16 + c16;
  const floatx4 zf = {0.f, 0.f, 0.f, 0.f};

  // --- int32-vs-int64 detection for char_seq ---
  if (tid == 0) det_s[0] = 0;
  __syncthreads();
  if (tid < 128 && cs[2 * tid + 1] != 0) atomicOr(&det_s[0], 1);
  __syncthreads();
  const bool is64 = (det_s[0] == 0);

  // --- staging ---
  for (int i = tid; i < 1152; i += 512) hist_s[7 * 1152 + i] = 0;   // h0 slot
  for (int i = tid; i < T1n * 4; i += 512) {
    int t = i >> 2, qq = i & 3;
    unsigned int pk = 0;
#pragma unroll
    for (int r = 0; r < 4; ++r) {
      long idx = (long)(b0 + qq * 4 + r) * T1n + t;
      int c = is64 ? cs[2 * idx] : cs[idx];
      pk |= ((unsigned int)(c & 255)) << (8 * r);
    }
    code4_s[i] = pk;
  }

  // --- TBL: tbl_s[g][v][j] = bf16( emb[v] @ W_gx[:64] + b_gx[j] + b_gh[j] ) ---
  // wave W8 handles v = W8 + 8k (emb reads wave-uniform -> scalar loads)
  for (int g = 0; g < 3; ++g) {
    const float* Wg = (g == 0) ? Wrx : (g == 1) ? Wzx : Whx;
    const float* bx = (g == 0) ? brx : (g == 1) ? bzx : bhx;
    const float* bh = (g == 0) ? brh : (g == 1) ? bzh : bhh;
    float acc[4] = {0.f, 0.f, 0.f, 0.f};
    float bias = bx[lane] + bh[lane];
    for (int d = 0; d < Hn; ++d) {
      float wv = Wg[(long)d * Hn + lane];
#pragma unroll
      for (int k = 0; k < 4; ++k)
        acc[k] += emb[(long)(W8 + 8 * k) * Hn + d] * wv;
    }
#pragma unroll
    for (int k = 0; k < 4; ++k)
      tbl_s[g * 2112 + (W8 + 8 * k) * 66 + lane] = f2bf(acc[k] + bias);
  }

  // --- PH per-lane: scan waves need r,h gates; aux waves need z gate ---
  float ph_a[4] = {0.f, 0.f, 0.f, 0.f};  // scan: r-gate | aux: z-gate
  float ph_h[4] = {0.f, 0.f, 0.f, 0.f};  // scan only
  {
    const float* Wa = isScan ? Wrx : Wzx;
    for (int p = 0; p < Pn; ++p) {
      float wa = Wa[(long)(Hn + p) * Hn + jcol];
      float wh = isScan ? Whx[(long)(Hn + p) * Hn + jcol] : 0.f;
#pragma unroll
      for (int r = 0; r < 4; ++r) {
        float xv = phon[(long)(b0 + q * 4 + r) * Pn + p];
        ph_a[r] += xv * wa;
        ph_h[r] += xv * wh;
      }
    }
  }

  // --- B-fragments (register-resident, t-invariant) ---
  short8 Ba0, Ba1;   // scan: W_rh | aux: W_zh
  short8 Bh0, Bh1;   // scan: W_hh
  short8 Bp0, Bp1;   // waves 4,5: W_proj (vocab tile W8-4)
  float bpj = 0.f;
  {
    const float* Wa = isScan ? Wrh : Wzh;
    Ba0 = load_bfrag(Wa, Hn, jcol, q * 8);
    Ba1 = load_bfrag(Wa, Hn, jcol, 32 + q * 8);
    Bh0 = Ba0; Bh1 = Ba1; Bp0 = Ba0; Bp1 = Ba1;
    if (isScan) {
      Bh0 = load_bfrag(Whh, Hn, jcol, q * 8);
      Bh1 = load_bfrag(Whh, Hn, jcol, 32 + q * 8);
    } else if (W8 < 6) {
      int vt = W8 - 4;
      Bp0 = load_bfrag(Wpj, Vn, vt * 16 + c16, q * 8);
      Bp1 = load_bfrag(Wpj, Vn, vt * 16 + c16, 32 + q * 8);
      bpj = bpj_g[vt * 16 + c16];
    }
  }

  float h[4] = {0.f, 0.f, 0.f, 0.f};
  float nll = 0.f, cnt = 0.f;

  __syncthreads();   // prologue done

  for (int t = 0; t < Tn; ++t) {
    const unsigned int pk = code4_s[t * 4 + q];
    // ===== interval A =====
    {
      const unsigned short* hp = &hist_s[((t + 7) & 7) * 1152];
      short8 a0 = *(const short8*)&hp[c16 * 72 + q * 8];
      short8 a1 = *(const short8*)&hp[c16 * 72 + 32 + q * 8];
      floatx4 acc = __builtin_amdgcn_mfma_f32_16x16x32_bf16(a0, Ba0, zf, 0, 0, 0);
      acc = __builtin_amdgcn_mfma_f32_16x16x32_bf16(a1, Ba1, acc, 0, 0, 0);
      if (isScan) {       // r-gate -> rh_s
#pragma unroll
        for (int r = 0; r < 4; ++r) {
          int cr = (pk >> (8 * r)) & 255;
          float xr = bf2f(tbl_s[0 * 2112 + cr * 66 + jcol]) + ph_a[r] + acc[r];
          rh_s[(q * 4 + r) * 72 + jcol] = f2bf(fast_sigmoid(xr) * h[r]);
        }
      } else {            // z-gate -> z_s (f32)
#pragma unroll
        for (int r = 0; r < 4; ++r) {
          int cr = (pk >> (8 * r)) & 255;
          float xz = bf2f(tbl_s[1 * 2112 + cr * 66 + jcol]) + ph_a[r] + acc[r];
          z_s[(q * 4 + r) * 68 + jcol] = fast_sigmoid(xz);
        }
      }
    }
    __syncthreads();  // A

    // ===== interval B =====
    if (isScan) {       // c-gate + h-update -> hist_s[t&7]
      short8 p0 = *(const short8*)&rh_s[c16 * 72 + q * 8];
      short8 p1 = *(const short8*)&rh_s[c16 * 72 + 32 + q * 8];
      floatx4 acc = __builtin_amdgcn_mfma_f32_16x16x32_bf16(p0, Bh0, zf, 0, 0, 0);
      acc = __builtin_amdgcn_mfma_f32_16x16x32_bf16(p1, Bh1, acc, 0, 0, 0);
      unsigned short* hw = &hist_s[(t & 7) * 1152];
#pragma unroll
      for (int r = 0; r < 4; ++r) {
        int cr = (pk >> (8 * r)) & 255;
        float xh = bf2f(tbl_s[2 * 2112 + cr * 66 + jcol]) + ph_h[r] + acc[r];
        float c = fast_tanh(xh);
        float zr = z_s[(q * 4 + r) * 68 + jcol];
        float hn = (1.f - zr) * h[r] + zr * c;
        h[r] = hn;
        hw[(q * 4 + r) * 72 + jcol] = f2bf(hn);
      }
    } else if (W8 < 6 && t > 0) {   // project h_{t-1} -> logit stage
      const unsigned short* hp = &hist_s[((t + 7) & 7) * 1152];
      short8 a0 = *(const short8*)&hp[c16 * 72 + q * 8];
      short8 a1 = *(const short8*)&hp[c16 * 72 + 32 + q * 8];
      floatx4 l = __builtin_amdgcn_mfma_f32_16x16x32_bf16(a0, Bp0, zf, 0, 0, 0);
      l = __builtin_amdgcn_mfma_f32_16x16x32_bf16(a1, Bp1, l, 0, 0, 0);
      float* pg = &logit_s[((t - 1) & 7) * 528];
      int vt = W8 - 4;
#pragma unroll
      for (int r = 0; r < 4; ++r)
        pg[(q * 4 + r) * 33 + vt * 16 + c16] = l[r] + bpj;
    }
    __syncthreads();  // B

    // ===== chunk tail: every 8 steps, all 8 waves =====
    if ((t & 7) == 7) {
      int p = t - 8 + W8;           // pages t-8 .. t-1
      if (p >= 0) {
        const float* pg = &logit_s[(p & 7) * 528];
        int v = lane & 31, hf = lane >> 5;
        unsigned int pk1 = 0;
#pragma unroll
        for (int i = 0; i < 8; ++i) {
          int m = i * 2 + hf;
          float lg = pg[m * 33 + v];
          float s = __expf(lg);
#pragma unroll
          for (int off = 16; off >= 1; off >>= 1) s += __shfl_xor(s, off);
          float lse = __logf(s);     // |logits| <= ~8, safe without max-sub
          outp[(((long)(b0 + m)) * Tn + p) * Vn + v] = lg;
          pk1 = code4_s[(p + 1) * 4 + (m >> 2)];
          int targ = (pk1 >> (8 * (m & 3))) & 255;
          if (targ != 0 && v == targ) { nll += lse - lg; cnt += 1.f; }
        }
      }
    }
  }

  // ===== epilogue: project + finalize t = 63 =====
  __syncthreads();
  if (W8 >= 4 && W8 < 6) {
    const unsigned short* hp = &hist_s[7 * 1152];   // h_63
    short8 a0 = *(const short8*)&hp[c16 * 72 + q * 8];
    short8 a1 = *(const short8*)&hp[c16 * 72 + 32 + q * 8];
    floatx4 l = __builtin_amdgcn_mfma_f32_16x16x32_bf16(a0, Bp0, zf, 0, 0, 0);
    l = __builtin_amdgcn_mfma_f32_16x16x32_bf16(a1, Bp1, l, 0, 0, 0);
    int vt = W8 - 4;
#pragma unroll
    for (int r = 0; r < 4; ++r)
      logit_s[7 * 528 + (q * 4 + r) * 33 + vt * 16 + c16] = l[r] + bpj;
  }
  __syncthreads();
  if (W8 == 0) {
    const float* pg = &logit_s[7 * 528];
    int v = lane & 31, hf = lane >> 5;
#pragma unroll
    for (int i = 0; i < 8; ++i) {
      int m = i * 2 + hf;
      float lg = pg[m * 33 + v];
      float s = __expf(lg);
#pragma unroll
      for (int off = 16; off >= 1; off >>= 1) s += __shfl_xor(s, off);
      float lse = __logf(s);
      outp[(((long)(b0 + m)) * Tn + 63) * Vn + v] = lg;
      unsigned int pk1 = code4_s[64 * 4 + (m >> 2)];
      int targ = (pk1 >> (8 * (m & 3))) & 255;
      if (targ != 0 && v == targ) { nll += lse - lg; cnt += 1.f; }
    }
  }

  // ===== reduction -> per-block ws slot =====
#pragma unroll
  for (int off = 32; off >= 1; off >>= 1) {
    nll += __shfl_xor(nll, off);
    cnt += __shfl_xor(cnt, off);
  }
  if (lane == 0) { red_s[W8] = nll; red_s[8 + W8] = cnt; }
  __syncthreads();
  if (tid == 0) {
    float n = 0.f, c = 0.f;
#pragma unroll
    for (int i = 0; i < 8; ++i) { n += red_s[i]; c += red_s[8 + i]; }
    ws[2 * blockIdx.x] = n;
    ws[2 * blockIdx.x + 1] = c;
  }
}

__global__ void loss_kernel(const float* __restrict__ ws, float* __restrict__ outp) {
  int lane = threadIdx.x;  // 64 threads
  float n = 0.f, c = 0.f;
  for (int i = lane; i < Bsz / 16; i += 64) { n += ws[2 * i]; c += ws[2 * i + 1]; }
#pragma unroll
  for (int off = 32; off >= 1; off >>= 1) {
    n += __shfl_xor(n, off);
    c += __shfl_xor(c, off);
  }
  if (lane == 0) outp[(size_t)Bsz * Tn * Vn] = n / fmaxf(c, 1.f);
}

extern "C" void kernel_launch(void* const* d_in, const int* in_sizes, int n_in,
                              void* d_out, int out_size, void* d_ws, size_t ws_size,
                              hipStream_t stream) {
  const float* phon = (const float*)d_in[0];
  const int*   cs   = (const int*)d_in[1];
  const float* emb  = (const float*)d_in[2];
  const float* Wrx  = (const float*)d_in[3];
  const float* brx  = (const float*)d_in[4];
  const float* Wrh  = (const float*)d_in[5];
  const float* brh  = (const float*)d_in[6];
  const float* Wzx  = (const float*)d_in[7];
  const float* bzx  = (const float*)d_in[8];
  const float* Wzh  = (const float*)d_in[9];
  const float* bzh  = (const float*)d_in[10];
  const float* Whx  = (const float*)d_in[11];
  const float* bhx  = (const float*)d_in[12];
  const float* Whh  = (const float*)d_in[13];
  const float* bhh  = (const float*)d_in[14];
  const float* Wpj  = (const float*)d_in[15];
  const float* bpj  = (const float*)d_in[16];
  float* ws = (float*)d_ws;

  hipLaunchKernelGGL(gru_kernel, dim3(Bsz / 16), dim3(512), 0, stream,
                     phon, cs, emb, Wrx, brx, Wrh, brh, Wzx, bzx, Wzh, bzh,
                     Whx, bhx, Whh, bhh, Wpj, bpj, ws, (float*)d_out);
  hipLaunchKernelGGL(loss_kernel, dim3(1), dim3(64), 0, stream, ws, (float*)d_out);
}